// Round 9
// baseline (286.514 us; speedup 1.0000x reference)
//
#include <hip/hip_runtime.h>

#define N_NODES 100000
#define N_EDGES 1200000
#define D 64
#define KEEP_PROB 0.7f
#define INV_KEEP (1.0f / KEEP_PROB)
#define NBUCK 1564         // ceil(N_NODES / 64) row-range buckets (row >> 6)
#define MAXB 1024          // spmm LDS sort chunk (mean bucket ~767)
#define PPART 256          // partition/hist blocks (contiguous chunks)
#define CHUNK4 1172        // ceil((N_EDGES/4) / PPART) int4-edges per block
#define NB64 ((NBUCK + 63) / 64)   // 25 blocks for sum/rebase

#define ALOAD_I(p)   __hip_atomic_load((p), __ATOMIC_RELAXED, __HIP_MEMORY_SCOPE_AGENT)
#define ALOAD_U64(p) __hip_atomic_load((p), __ATOMIC_RELAXED, __HIP_MEMORY_SCOPE_AGENT)

// ---------------------------------------------------------------------------
__global__ __launch_bounds__(256) void zero_kernel(float4* __restrict__ p, int n4) {
    int i = blockIdx.x * 256 + threadIdx.x;
    if (i < n4) p[i] = make_float4(0.f, 0.f, 0.f, 0.f);
}

// ---------------------------------------------------------------------------
// Build 1: per-block bucket histogram over CONTIGUOUS chunks (same
// decomposition as partition_kernel). Writes ONLY h[p][b] (coalesced).
__global__ __launch_bounds__(256) void bucket_hist_kernel(const int4* __restrict__ rows4,
                                                          int* __restrict__ h) {
    __shared__ int hh[NBUCK];
    int p = blockIdx.x;
    int t = threadIdx.x;
    for (int i = t; i < NBUCK; i += 256) hh[i] = 0;
    __syncthreads();
    int i0 = p * CHUNK4;
    int i1 = i0 + CHUNK4;
    if (i1 > N_EDGES / 4) i1 = N_EDGES / 4;
    for (int i = i0 + t; i < i1; i += 256) {
        int4 r = rows4[i];
        atomicAdd(&hh[r.x >> 6], 1);
        atomicAdd(&hh[r.y >> 6], 1);
        atomicAdd(&hh[r.z >> 6], 1);
        atomicAdd(&hh[r.w >> 6], 1);
    }
    __syncthreads();
    int* hp = h + p * NBUCK;
    for (int i = t; i < NBUCK; i += 256) hp[i] = hh[i];
}

// ---------------------------------------------------------------------------
// Build 1.5: total[b] = sum_p h[p][b]. 64 buckets/block, 4 chunk-threads.
__global__ __launch_bounds__(256) void sum_kernel(const int* __restrict__ h,
                                                  int* __restrict__ total) {
    __shared__ int sq[4][64];
    int t = threadIdx.x;
    int bo = t & 63, q = t >> 6;
    int b = blockIdx.x * 64 + bo;
    int s = 0;
    if (b < NBUCK) {
        for (int p = q * 64; p < q * 64 + 64; ++p) s += h[p * NBUCK + b];
    }
    sq[q][bo] = s;
    __syncthreads();
    if (q == 0 && b < NBUCK)
        total[b] = sq[0][bo] + sq[1][bo] + sq[2][bo] + sq[3][bo];
}

// ---------------------------------------------------------------------------
// Build 2: single-block exclusive scan of dense totals -> bbase.
__global__ __launch_bounds__(256) void bucket_scan_kernel(const int* __restrict__ total,
                                                          int* __restrict__ bbase) {
    __shared__ int part[256];
    const int CH = 7;   // 256*7 = 1792 >= NBUCK
    int t = threadIdx.x;
    int e[CH]; int s = 0;
    #pragma unroll
    for (int k = 0; k < CH; ++k) {
        int j = t * CH + k;
        e[k] = (j < NBUCK) ? total[j] : 0;
        s += e[k];
    }
    part[t] = s;
    __syncthreads();
    for (int d = 1; d < 256; d <<= 1) {
        int w = (t >= d) ? part[t - d] : 0;
        __syncthreads();
        part[t] += w;
        __syncthreads();
    }
    int run = part[t] - s;
    #pragma unroll
    for (int k = 0; k < CH; ++k) {
        int j = t * CH + k;
        if (j < NBUCK) { bbase[j] = run; run += e[k]; }
    }
    if (t == 255) bbase[NBUCK] = run;            // == N_EDGES
}

// ---------------------------------------------------------------------------
// Build 2.5: h[p][b] <- bbase[b] + sum_{q<p} h[q][b]. 64 buckets/block,
// 4 chunk-threads per bucket: chunk sums -> LDS combine -> rewrite.
__global__ __launch_bounds__(256) void rebase_kernel(int* __restrict__ h,
                                                     const int* __restrict__ bbase) {
    __shared__ int sq[4][64];
    int t = threadIdx.x;
    int bo = t & 63, q = t >> 6;
    int b = blockIdx.x * 64 + bo;
    bool ok = (b < NBUCK);
    int s = 0;
    if (ok) {
        for (int p = q * 64; p < q * 64 + 64; ++p) s += h[p * NBUCK + b];
    }
    sq[q][bo] = s;
    __syncthreads();
    if (ok) {
        int run = bbase[b];
        for (int qq = 0; qq < q; ++qq) run += sq[qq][bo];
        for (int p = q * 64; p < q * 64 + 64; ++p) {
            int idx = p * NBUCK + b;
            int c = h[idx];
            h[idx] = run;
            run += c;
        }
    }
}

// ---------------------------------------------------------------------------
// Build 3: partition edges into buckets, emitting per-layer SoA 8-B records
// (col | lr<<17, v) directly into s0/s1 (shared cursor). The spmm now sorts
// in-block, so the finalize pass is DELETED (-19.2 MB R, -19.2 MB W,
// -1 launch). Atomic-free globally; runs stay per-(block,bucket) contiguous.
__global__ __launch_bounds__(256) void partition_kernel(
    const int4*   __restrict__ rows4,
    const int4*   __restrict__ cols4,
    const float4* __restrict__ vals4,
    const float4* __restrict__ u04,
    const float4* __restrict__ u14,
    const int*    __restrict__ h,
    unsigned long long* __restrict__ s0,
    unsigned long long* __restrict__ s1) {
    __shared__ int cur[NBUCK];
    int p = blockIdx.x;
    int t = threadIdx.x;
    const int* hp = h + p * NBUCK;
    for (int i = t; i < NBUCK; i += 256) cur[i] = hp[i];
    __syncthreads();

    int i0 = p * CHUNK4;
    int i1 = i0 + CHUNK4;
    if (i1 > N_EDGES / 4) i1 = N_EDGES / 4;
    for (int i = i0 + t; i < i1; i += 256) {
        int4   r  = rows4[i];
        int4   c  = cols4[i];
        float4 v  = vals4[i];
        float4 u0 = u04[i];
        float4 u1 = u14[i];

        int p0 = atomicAdd(&cur[r.x >> 6], 1);
        int p1 = atomicAdd(&cur[r.y >> 6], 1);
        int p2 = atomicAdd(&cur[r.z >> 6], 1);
        int p3 = atomicAdd(&cur[r.w >> 6], 1);

        float vv; unsigned cr, v0b, v1b;
        vv = v.x * INV_KEEP;
        cr = (unsigned)c.x | (((unsigned)r.x & 63u) << 17);
        v0b = __float_as_uint((u0.x + KEEP_PROB >= 1.0f) ? vv : 0.f);
        v1b = __float_as_uint((u1.x + KEEP_PROB >= 1.0f) ? vv : 0.f);
        s0[p0] = ((unsigned long long)v0b << 32) | cr;
        s1[p0] = ((unsigned long long)v1b << 32) | cr;
        vv = v.y * INV_KEEP;
        cr = (unsigned)c.y | (((unsigned)r.y & 63u) << 17);
        v0b = __float_as_uint((u0.y + KEEP_PROB >= 1.0f) ? vv : 0.f);
        v1b = __float_as_uint((u1.y + KEEP_PROB >= 1.0f) ? vv : 0.f);
        s0[p1] = ((unsigned long long)v0b << 32) | cr;
        s1[p1] = ((unsigned long long)v1b << 32) | cr;
        vv = v.z * INV_KEEP;
        cr = (unsigned)c.z | (((unsigned)r.z & 63u) << 17);
        v0b = __float_as_uint((u0.z + KEEP_PROB >= 1.0f) ? vv : 0.f);
        v1b = __float_as_uint((u1.z + KEEP_PROB >= 1.0f) ? vv : 0.f);
        s0[p2] = ((unsigned long long)v0b << 32) | cr;
        s1[p2] = ((unsigned long long)v1b << 32) | cr;
        vv = v.w * INV_KEEP;
        cr = (unsigned)c.w | (((unsigned)r.w & 63u) << 17);
        v0b = __float_as_uint((u0.w + KEEP_PROB >= 1.0f) ? vv : 0.f);
        v1b = __float_as_uint((u1.w + KEEP_PROB >= 1.0f) ? vv : 0.f);
        s0[p3] = ((unsigned long long)v0b << 32) | cr;
        s1[p3] = ((unsigned long long)v1b << 32) | cr;
    }
}

// ---------------------------------------------------------------------------
// SpMM with in-block counting sort (finalize folded in). One block per
// bucket. Per MAXB-chunk: LDS hist of lr -> prefix -> scatter sorted
// records into sl[] (8 KB LDS) -> R8-proven flat ownership-accumulate
// reading edges FROM LDS. accs updates are RMW (+=) so chunks compose;
// within a chunk each row has a unique owner, chunks are barrier-separated.
// No fp LDS atomics in the hot loop (R6 lesson). Int LDS atomics only in
// the (short) sort passes.
__global__ __launch_bounds__(256) void spmm_sort_kernel(
    const float4* __restrict__ x_in,
    const unsigned long long* __restrict__ s,
    const int*   __restrict__ bbase,
    float4*      __restrict__ io,
    int layer) {
    __shared__ float accs[64 * 64];           // 16 KB [lr][col]
    __shared__ unsigned long long sl[MAXB];   // 8 KB sorted (cr,v)
    __shared__ float partb[16][64];           // boundary-prefix partials
    __shared__ int cnt[64], cur[64], pref[64], prow[16];
    int b = blockIdx.x;
    int t = threadIdx.x;
    int base = bbase[b];
    int size = bbase[b + 1] - base;
    int row0 = b << 6;

    #pragma unroll
    for (int i = 0; i < 4; ++i)
        *(float4*)&accs[(i * 256 + t) * 4] = make_float4(0.f, 0.f, 0.f, 0.f);
    __syncthreads();

    int g   = t >> 4;                 // lane-group 0..15
    int l16 = t & 15;
    int j0  = l16 << 2;

    for (int c0 = 0; c0 < size; c0 += MAXB) {
        int csize = size - c0; if (csize > MAXB) csize = MAXB;
        if (t < 64) cnt[t] = 0;
        if (t < 16) prow[t] = -1;
        __syncthreads();
        // pass 1: lr histogram (int LDS atomics — fast path)
        for (int i = t; i < csize; i += 256) {
            unsigned lo = (unsigned)ALOAD_U64(&s[base + c0 + i]);
            atomicAdd(&cnt[lo >> 17], 1);
        }
        __syncthreads();
        int v = (t < 64) ? cnt[t] : 0;
        if (t < 64) pref[t] = v;
        __syncthreads();
        for (int d = 1; d < 64; d <<= 1) {
            int w = (t >= d && t < 64) ? pref[t - d] : 0;
            __syncthreads();
            if (t < 64) pref[t] += w;
            __syncthreads();
        }
        if (t < 64) cur[t] = pref[t] - v;
        __syncthreads();
        // pass 2: scatter sorted into sl (source L2-hot from pass 1)
        for (int i = t; i < csize; i += 256) {
            unsigned long long rec = ALOAD_U64(&s[base + c0 + i]);
            int lr = (int)((unsigned)rec >> 17);
            int slot = atomicAdd(&cur[lr], 1);
            sl[slot] = rec;
        }
        __syncthreads();

        // flat accumulate over sl[0..csize): 16 balanced lane-group slices
        int e0 = (csize * g) >> 4;
        int e1 = (csize * (g + 1)) >> 4;
        bool partial = false;
        if (e0 < e1 && e0 > 0) {
            unsigned plo = (unsigned)sl[e0 - 1];
            unsigned flo = (unsigned)sl[e0];
            partial = ((plo >> 17) == (flo >> 17));
        }
        float4 acc = make_float4(0.f, 0.f, 0.f, 0.f);
        int curR = -1;
        bool first = true;
        for (int e = e0; e < e1; ++e) {
            unsigned long long rec = sl[e];   // LDS broadcast per group
            unsigned lo = (unsigned)rec;
            float vv = __uint_as_float((unsigned)(rec >> 32));
            int lr = (int)(lo >> 17);
            if (lr != curR) {                 // group-uniform branch
                if (curR >= 0) {
                    if (first && partial) {
                        *(float4*)&partb[g][j0] = acc;
                        if (l16 == 0) prow[g] = curR;
                    } else {
                        float4* p = (float4*)&accs[(curR << 6) + j0];
                        float4 o = *p;        // RMW: chunks compose
                        o.x += acc.x; o.y += acc.y; o.z += acc.z; o.w += acc.w;
                        *p = o;
                    }
                    first = false;
                }
                acc = make_float4(0.f, 0.f, 0.f, 0.f);
                curR = lr;
            }
            int c  = (int)(lo & 0x1ffffu);
            int cc = (vv != 0.f) ? c : 0;     // dropped edges -> hot row 0
            float4 x = x_in[(cc << 4) + l16];
            acc.x = fmaf(vv, x.x, acc.x);
            acc.y = fmaf(vv, x.y, acc.y);
            acc.z = fmaf(vv, x.z, acc.z);
            acc.w = fmaf(vv, x.w, acc.w);
        }
        if (curR >= 0) {                      // tail flush
            if (first && partial) {
                *(float4*)&partb[g][j0] = acc;
                if (l16 == 0) prow[g] = curR;
            } else {
                float4* p = (float4*)&accs[(curR << 6) + j0];
                float4 o = *p;
                o.x += acc.x; o.y += acc.y; o.z += acc.z; o.w += acc.w;
                *p = o;
            }
        }
        __syncthreads();
        // merge boundary partials: 16 lanes, sequential over groups
        if (t < 16) {
            int jj = t << 2;
            for (int gg = 1; gg < 16; ++gg) {
                int pr = prow[gg];
                if (pr >= 0) {
                    float* a = &accs[(pr << 6) + jj];
                    const float* p = &partb[gg][jj];
                    a[0] += p[0]; a[1] += p[1]; a[2] += p[2]; a[3] += p[3];
                }
            }
        }
        __syncthreads();
    }

    // writeback: 1024 float4 granules, coalesced
    #pragma unroll
    for (int i = 0; i < 4; ++i) {
        int idx = i * 256 + t;        // 0..1023
        int lr = idx >> 4;
        int gg = idx & 15;
        int row = row0 + lr;
        if (row < N_NODES) {
            float4 sv = *(const float4*)&accs[(lr << 6) + (gg << 2)];
            int o = (row << 4) + gg;
            if (layer == 0) {
                io[o] = sv;
            } else {
                float4 p = io[o];
                p.x = (p.x + sv.x) * (1.0f / 3.0f);
                p.y = (p.y + sv.y) * (1.0f / 3.0f);
                p.z = (p.z + sv.z) * (1.0f / 3.0f);
                p.w = (p.w + sv.w) * (1.0f / 3.0f);
                io[o] = p;
            }
        }
    }
}

// ---------------------------------------------------------------------------
// out[n,j] = b[j] + sum_k emb[n,k]*W[j,k] + x1[n,j]
// Register-blocked: 64 nodes/block, 4x4 tile/thread; launch_bounds(256,4)
// caps VGPR at 128 (R3 lesson: full unroll blew to 240 -> 8.8% occupancy).
#define FMA4(A, E, WV) \
    A.x = fmaf(E, WV.x, A.x); A.y = fmaf(E, WV.y, A.y); \
    A.z = fmaf(E, WV.z, A.z); A.w = fmaf(E, WV.w, A.w);

__global__ __launch_bounds__(256, 4) void fc_add_kernel(
    const float* __restrict__ emb,
    const float* __restrict__ W,
    const float* __restrict__ b,
    const float* __restrict__ x1,
    float*       __restrict__ out) {
    __shared__ float Wt[D * 68];    // Wt[k][j] = W[j][k], row pad 68
    __shared__ float Es[64 * 68];   // Es[n][k],           row pad 68

    int t = threadIdx.x;
    int n0 = blockIdx.x * 64;

    #pragma unroll
    for (int i = 0; i < 16; ++i) {
        int idx = i * 256 + t;          // = j*64 + k
        Wt[(idx & 63) * 68 + (idx >> 6)] = W[idx];
    }
    #pragma unroll
    for (int i = 0; i < 4; ++i) {
        int idx4 = i * 256 + t;
        int n = idx4 >> 4;              // 0..63
        int k0 = (idx4 & 15) * 4;
        float4 v = make_float4(0.f, 0.f, 0.f, 0.f);
        if (n0 + n < N_NODES) v = *(const float4*)&emb[(n0 + n) * D + k0];
        *(float4*)&Es[n * 68 + k0] = v;
    }
    __syncthreads();

    int tj = t & 15;                    // j-group: j0 = 4*tj
    int tn = t >> 4;                    // node-group: nodes 4*tn .. 4*tn+3
    int j0 = tj * 4;

    float4 bb = *(const float4*)&b[j0];
    float4 acc[4];
    #pragma unroll
    for (int i = 0; i < 4; ++i) acc[i] = bb;

    const float* es = &Es[(tn * 4) * 68];
    #pragma unroll 4
    for (int kc = 0; kc < 16; ++kc) {
        int k = kc * 4;
        float4 w0 = *(const float4*)&Wt[(k + 0) * 68 + j0];
        float4 w1 = *(const float4*)&Wt[(k + 1) * 68 + j0];
        float4 w2 = *(const float4*)&Wt[(k + 2) * 68 + j0];
        float4 w3 = *(const float4*)&Wt[(k + 3) * 68 + j0];
        float4 e0 = *(const float4*)&es[0 * 68 + k];
        float4 e1 = *(const float4*)&es[1 * 68 + k];
        float4 e2 = *(const float4*)&es[2 * 68 + k];
        float4 e3 = *(const float4*)&es[3 * 68 + k];
        FMA4(acc[0], e0.x, w0); FMA4(acc[0], e0.y, w1);
        FMA4(acc[0], e0.z, w2); FMA4(acc[0], e0.w, w3);
        FMA4(acc[1], e1.x, w0); FMA4(acc[1], e1.y, w1);
        FMA4(acc[1], e1.z, w2); FMA4(acc[1], e1.w, w3);
        FMA4(acc[2], e2.x, w0); FMA4(acc[2], e2.y, w1);
        FMA4(acc[2], e2.z, w2); FMA4(acc[2], e2.w, w3);
        FMA4(acc[3], e3.x, w0); FMA4(acc[3], e3.y, w1);
        FMA4(acc[3], e3.z, w2); FMA4(acc[3], e3.w, w3);
    }

    #pragma unroll
    for (int i = 0; i < 4; ++i) {
        int n = n0 + tn * 4 + i;
        if (n < N_NODES) {
            float4 p = *(const float4*)&x1[n * D + j0];
            float4 a = acc[i];
            a.x += p.x; a.y += p.y; a.z += p.z; a.w += p.w;
            *(float4*)&out[n * D + j0] = a;
        }
    }
}

// ---------------------------------------------------------------------------
// Fallback (atomic path, replay-proven) if ws too small
__global__ __launch_bounds__(256) void spmm_atomic_kernel(
    const float* __restrict__ x_in,
    const float* __restrict__ vals,
    const float* __restrict__ drop_u,
    const int*   __restrict__ rows,
    const int*   __restrict__ cols,
    float*       __restrict__ x_out) {
    int wave = (blockIdx.x * 256 + threadIdx.x) >> 6;
    int lane = threadIdx.x & 63;
    if (wave >= N_EDGES) return;
    float u = drop_u[wave];
    if (u + KEEP_PROB < 1.0f) return;
    float v = vals[wave] * INV_KEEP;
    atomicAdd(&x_out[rows[wave] * D + lane], v * x_in[cols[wave] * D + lane]);
}

__global__ __launch_bounds__(256) void scale_kernel(float4* __restrict__ p, int n4) {
    int i = blockIdx.x * 256 + threadIdx.x;
    if (i < n4) {
        float4 v = p[i];
        v.x *= (1.f/3.f); v.y *= (1.f/3.f); v.z *= (1.f/3.f); v.w *= (1.f/3.f);
        p[i] = v;
    }
}

// ---------------------------------------------------------------------------
extern "C" void kernel_launch(void* const* d_in, const int* in_sizes, int n_in,
                              void* d_out, int out_size, void* d_ws, size_t ws_size,
                              hipStream_t stream) {
    const float* all_emb = (const float*)d_in[0];
    const float* W       = (const float*)d_in[1];
    const float* b       = (const float*)d_in[2];
    const float* vals    = (const float*)d_in[3];
    const float* drop_u  = (const float*)d_in[4];   // [2, E]
    const int*   rows    = (const int*)d_in[5];
    const int*   cols    = (const int*)d_in[6];

    float* out = (float*)d_out;

    // workspace layout:
    //   [0, 25.6M)       x1 output; h[PPART][NBUCK] lives at +19.2M (dead
    //                    before spmm-0 overwrites the region with x1)
    //   [26.0M, 35.6M)   s0 — layer-0 SoA 8-B edge records
    //   [35.6M, 45.2M)   s1 — layer-1 SoA 8-B edge records
    //   then total[], bbase[]
    char* ws = (char*)d_ws;
    float* x1       = (float*)(ws);
    int*   h        = (int*)  (ws + 19200000);            // 1,601,536 B
    unsigned long long* s0 = (unsigned long long*)(ws + 26000064);  // 9.6 MB
    unsigned long long* s1 = (unsigned long long*)(ws + 35600064);  // 9.6 MB
    int*   total    = (int*)  (ws + 45200064);            // 6,256 B
    int*   bbase    = (int*)  (ws + 45206320);            // 6,272 B
    const size_t WS_NEEDED = 45406528;   // unchanged (proven capacity)

    const int n4 = N_NODES * D / 4;
    const int zb = (n4 + 255) / 256;
    const int fc_blocks = (N_NODES + 63) / 64;            // 1563

    if (ws_size >= WS_NEEDED) {
        bucket_hist_kernel<<<PPART, 256, 0, stream>>>((const int4*)rows, h);
        sum_kernel<<<NB64, 256, 0, stream>>>(h, total);
        bucket_scan_kernel<<<1, 256, 0, stream>>>(total, bbase);
        rebase_kernel<<<NB64, 256, 0, stream>>>(h, bbase);
        partition_kernel<<<PPART, 256, 0, stream>>>(
            (const int4*)rows, (const int4*)cols, (const float4*)vals,
            (const float4*)drop_u, (const float4*)(drop_u + N_EDGES),
            h, s0, s1);
        // layer 0: x1 = A1 @ all_emb   (overwrites h region)
        spmm_sort_kernel<<<NBUCK, 256, 0, stream>>>(
            (const float4*)all_emb, s0, bbase, (float4*)x1, 0);
        // out = fc(all_emb) + x1
        fc_add_kernel<<<fc_blocks, 256, 0, stream>>>(all_emb, W, b, x1, out);
        // layer 1 (fused /3): out = (out + A2 @ x1) / 3
        spmm_sort_kernel<<<NBUCK, 256, 0, stream>>>(
            (const float4*)x1, s1, bbase, (float4*)out, 1);
    } else {
        // fallback: proven atomic path
        const int spmm_blocks = (N_EDGES + 3) / 4;
        zero_kernel<<<zb, 256, 0, stream>>>((float4*)x1, n4);
        spmm_atomic_kernel<<<spmm_blocks, 256, 0, stream>>>(all_emb, vals, drop_u,
                                                            rows, cols, x1);
        fc_add_kernel<<<fc_blocks, 256, 0, stream>>>(all_emb, W, b, x1, out);
        spmm_atomic_kernel<<<spmm_blocks, 256, 0, stream>>>(x1, vals,
                                                            drop_u + N_EDGES,
                                                            rows, cols, out);
        scale_kernel<<<zb, 256, 0, stream>>>((float4*)out, n4);
    }
}